// Round 1
// baseline (1117.158 us; speedup 1.0000x reference)
//
#include <hip/hip_runtime.h>

// Fixed-point stochastic quantize: out = clip(floor(x/sigma + r)*sigma, t_min, t_max)
// WL=8, FL=4  ->  sigma = 2^-4 = 0.0625, t_max = 8 - sigma = 7.9375, t_min = -8
// Elementwise over 134M fp32 elements: memory-bound (1.5 GiB traffic / launch).

__global__ __launch_bounds__(256) void quantize_sr_kernel(
    const float4* __restrict__ x4,
    const float4* __restrict__ r4,
    float4* __restrict__ o4,
    int n4,
    const float* __restrict__ x,
    const float* __restrict__ r,
    float* __restrict__ o,
    int n)
{
    constexpr float INV_SIGMA = 16.0f;
    constexpr float SIGMA     = 0.0625f;
    constexpr float T_MAX     = 7.9375f;
    constexpr float T_MIN     = -8.0f;

    int i = blockIdx.x * blockDim.x + threadIdx.x;
    if (i < n4) {
        float4 xv = x4[i];
        float4 rv = r4[i];
        float4 ov;
        // x*16 is exact (pow2), so fmaf == (x/sigma)+r with identical rounding.
        ov.x = fminf(fmaxf(floorf(fmaf(xv.x, INV_SIGMA, rv.x)) * SIGMA, T_MIN), T_MAX);
        ov.y = fminf(fmaxf(floorf(fmaf(xv.y, INV_SIGMA, rv.y)) * SIGMA, T_MIN), T_MAX);
        ov.z = fminf(fmaxf(floorf(fmaf(xv.z, INV_SIGMA, rv.z)) * SIGMA, T_MIN), T_MAX);
        ov.w = fminf(fmaxf(floorf(fmaf(xv.w, INV_SIGMA, rv.w)) * SIGMA, T_MIN), T_MAX);
        o4[i] = ov;
    }
    // Tail (n not divisible by 4) — not hit for this shape but kept for safety.
    if (i == 0) {
        for (int k = n4 * 4; k < n; ++k) {
            o[k] = fminf(fmaxf(floorf(fmaf(x[k], INV_SIGMA, r[k])) * SIGMA, T_MIN), T_MAX);
        }
    }
}

extern "C" void kernel_launch(void* const* d_in, const int* in_sizes, int n_in,
                              void* d_out, int out_size, void* d_ws, size_t ws_size,
                              hipStream_t stream) {
    const float* x = (const float*)d_in[0];
    const float* r = (const float*)d_in[1];
    float* o = (float*)d_out;
    int n = in_sizes[0];
    int n4 = n >> 2;

    int block = 256;
    int grid = (n4 + block - 1) / block;
    quantize_sr_kernel<<<grid, block, 0, stream>>>(
        (const float4*)x, (const float4*)r, (float4*)o, n4,
        x, r, o, n);
}